// Round 3
// baseline (199.692 us; speedup 1.0000x reference)
//
#include <hip/hip_runtime.h>
#include <hip/hip_bf16.h>

#define B_  4
#define C_  256
#define CB_ 32
#define N_  4096

typedef short bf16x8 __attribute__((ext_vector_type(8)));
typedef float f32x4  __attribute__((ext_vector_type(4)));

static __device__ __forceinline__ bf16x8 ld_bf8(const __hip_bfloat16* p) {
    return *reinterpret_cast<const bf16x8*>(p);
}

// ---------------------------------------------------------------------------
// Workspace layout (12 MiB total):
//   Wc    bf16 [320][256]  @ 0x000000 (160 KiB)  rows 0..31=Wq,32..63=Wk,64..319=Wv
//   qt    bf16 [B][N][32]  @ 0x040000 (1 MiB)
//   kt    bf16 [B][N][32]  @ 0x140000 (1 MiB)
//   rowM  fp32 [B][N]      @ 0x240000 (64 KiB)
//   rowZi fp32 [B][N]      @ 0x250000 (64 KiB)
//   pM    fp32 [4][B][N]   @ 0x260000 (256 KiB)
//   pZ    fp32 [4][B][N]   @ 0x2A0000 (256 KiB)
//   v     bf16 [B][C][N]   @ 0x400000 (8 MiB)
// ---------------------------------------------------------------------------

__global__ __launch_bounds__(256) void wconv(
    const float* __restrict__ Wq, const float* __restrict__ Wk,
    const float* __restrict__ Wv, __hip_bfloat16* __restrict__ Wc)
{
    int idx = (blockIdx.x * 256 + threadIdx.x) * 4;
    if (idx >= 320 * 256) return;
    int o = idx >> 8, c = idx & 255;
    const float* src = o < 32 ? Wq + o * 256 + c
                     : o < 64 ? Wk + (o - 32) * 256 + c
                              : Wv + (o - 64) * 256 + c;
    float4 f = *reinterpret_cast<const float4*>(src);
    union { __hip_bfloat16 h[4]; uint2 u; } pk;
    pk.h[0] = __float2bfloat16(f.x); pk.h[1] = __float2bfloat16(f.y);
    pk.h[2] = __float2bfloat16(f.z); pk.h[3] = __float2bfloat16(f.w);
    *reinterpret_cast<uint2*>(Wc + idx) = pk.u;
}

// Fused QKV projection, MFMA. Block: 32 n, all 320 output rows, 4 waves.
__global__ __launch_bounds__(256) void qkv_gemm(
    const float* __restrict__ x, const __hip_bfloat16* __restrict__ Wc,
    const float* __restrict__ bq, const float* __restrict__ bk,
    const float* __restrict__ bv,
    __hip_bfloat16* __restrict__ qt, __hip_bfloat16* __restrict__ kt,
    __hip_bfloat16* __restrict__ v)
{
    const int b = blockIdx.y, n0 = blockIdx.x * 32;
    const int tid = threadIdx.x, lane = tid & 63, w = tid >> 6;
    const int lg = lane >> 4, lr = lane & 15;
    __shared__ __attribute__((aligned(16))) __hip_bfloat16 T[2][32][40]; // [n][c]
    const float* xb = x + (size_t)b * C_ * N_;

    f32x4 acc[5][2] = {};
    for (int s = 0; s < 8; ++s) {
        const int c0 = s * 32, buf = s & 1;
        {   // stage x[c0..c0+32)[n0..n0+32) transposed, bf16: 1 float4/thread
            int cl = tid >> 3, n4 = (tid & 7) * 4;
            float4 f = *reinterpret_cast<const float4*>(
                &xb[(size_t)(c0 + cl) * N_ + n0 + n4]);
            T[buf][n4 + 0][cl] = __float2bfloat16(f.x);
            T[buf][n4 + 1][cl] = __float2bfloat16(f.y);
            T[buf][n4 + 2][cl] = __float2bfloat16(f.z);
            T[buf][n4 + 3][cl] = __float2bfloat16(f.w);
        }
        __syncthreads();
        bf16x8 bfr[2];
#pragma unroll
        for (int nf = 0; nf < 2; ++nf)
            bfr[nf] = *reinterpret_cast<const bf16x8*>(&T[buf][nf * 16 + lr][lg * 8]);
#pragma unroll
        for (int t = 0; t < 5; ++t) {
            const int of = w + 4 * t;
            bf16x8 af = ld_bf8(Wc + (size_t)(of * 16 + lr) * 256 + c0 + lg * 8);
#pragma unroll
            for (int nf = 0; nf < 2; ++nf)
                acc[t][nf] = __builtin_amdgcn_mfma_f32_16x16x32_bf16(af, bfr[nf], acc[t][nf], 0, 0, 0);
        }
        __syncthreads();
    }
#pragma unroll
    for (int t = 0; t < 5; ++t) {
        const int of = w + 4 * t, ob = of * 16 + lg * 4;
        float bias[4];
#pragma unroll
        for (int i = 0; i < 4; ++i) {
            int o = ob + i;
            bias[i] = o < 32 ? bq[o] : o < 64 ? bk[o - 32] : bv[o - 64];
        }
#pragma unroll
        for (int nf = 0; nf < 2; ++nf) {
            const int n = n0 + nf * 16 + lr;
            if (ob < 64) {
                union { __hip_bfloat16 h[4]; uint2 u; } pk;
#pragma unroll
                for (int i = 0; i < 4; ++i)
                    pk.h[i] = __float2bfloat16(acc[t][nf][i] + bias[i]);
                __hip_bfloat16* dst = ob < 32
                    ? qt + ((size_t)b * N_ + n) * CB_ + ob
                    : kt + ((size_t)b * N_ + n) * CB_ + (ob - 32);
                *reinterpret_cast<uint2*>(dst) = pk.u;
            } else {
#pragma unroll
                for (int i = 0; i < 4; ++i)
                    v[((size_t)b * C_ + (ob - 64 + i)) * N_ + n] =
                        __float2bfloat16(acc[t][nf][i] + bias[i]);
            }
        }
    }
}

// Partial row stats over an n-quarter. Wave w: 16 m-rows.
__global__ __launch_bounds__(256) void row_stats_part(
    const __hip_bfloat16* __restrict__ qt, const __hip_bfloat16* __restrict__ kt,
    float* __restrict__ pM, float* __restrict__ pZ)
{
    const int m0 = blockIdx.x * 64, s = blockIdx.y, b = blockIdx.z;
    const int tid = threadIdx.x, lane = tid & 63, w = tid >> 6;
    const int lg = lane >> 4, lr = lane & 15;
    const __hip_bfloat16* qtb = qt + (size_t)b * N_ * CB_;
    const __hip_bfloat16* ktb = kt + (size_t)b * N_ * CB_;
    const int mrow = m0 + w * 16;
    bf16x8 qf = ld_bf8(qtb + (size_t)(mrow + lr) * CB_ + lg * 8);
    float rm[4] = {-1e30f, -1e30f, -1e30f, -1e30f};
    float rz[4] = {0.f, 0.f, 0.f, 0.f};
    const f32x4 zero = {0.f, 0.f, 0.f, 0.f};
    const int nbeg = s * (N_ / 4);
    for (int n = nbeg; n < nbeg + N_ / 4; n += 64) {
        f32x4 sf[4];
#pragma unroll
        for (int nf = 0; nf < 4; ++nf) {
            bf16x8 kf = ld_bf8(ktb + (size_t)(n + nf * 16 + lr) * CB_ + lg * 8);
            sf[nf] = __builtin_amdgcn_mfma_f32_16x16x32_bf16(qf, kf, zero, 0, 0, 0);
        }
#pragma unroll
        for (int i = 0; i < 4; ++i) {
            float tm = fmaxf(fmaxf(sf[0][i], sf[1][i]), fmaxf(sf[2][i], sf[3][i]));
            if (tm > rm[i]) { rz[i] *= __expf(rm[i] - tm); rm[i] = tm; }
            rz[i] += __expf(sf[0][i] - rm[i]) + __expf(sf[1][i] - rm[i]) +
                     __expf(sf[2][i] - rm[i]) + __expf(sf[3][i] - rm[i]);
        }
    }
#pragma unroll
    for (int off = 1; off < 16; off <<= 1) {
#pragma unroll
        for (int i = 0; i < 4; ++i) {
            float om = __shfl_xor(rm[i], off);
            float oz = __shfl_xor(rz[i], off);
            float nm = fmaxf(rm[i], om);
            rz[i] = rz[i] * __expf(rm[i] - nm) + oz * __expf(om - nm);
            rm[i] = nm;
        }
    }
    if (lr == 0) {
        const size_t base = ((size_t)s * B_ + b) * N_ + mrow + lg * 4;
#pragma unroll
        for (int i = 0; i < 4; ++i) { pM[base + i] = rm[i]; pZ[base + i] = rz[i]; }
    }
}

__global__ __launch_bounds__(256) void stats_combine(
    const float* __restrict__ pM, const float* __restrict__ pZ,
    float* __restrict__ rowM, float* __restrict__ rowZi)
{
    const int i = blockIdx.x * 256 + threadIdx.x;   // over B_*N_
    const int BN = B_ * N_;
    float m0 = pM[i], m1 = pM[BN + i], m2 = pM[2 * BN + i], m3 = pM[3 * BN + i];
    float M = fmaxf(fmaxf(m0, m1), fmaxf(m2, m3));
    float Z = pZ[i]          * __expf(m0 - M) + pZ[BN + i]     * __expf(m1 - M)
            + pZ[2 * BN + i] * __expf(m2 - M) + pZ[3 * BN + i] * __expf(m3 - M);
    rowM[i] = M;
    rowZi[i] = 1.0f / Z;
}

// out[c,n] = x[c,n] + sum_m v[c,m] * exp(S(m,n)-M(m))*Zi(m).
// Block: 64c x 64n, 4 waves; wave w owns m-slice [m0+w*16, m0+w*16+16) each step.
// P stays in registers (S C-frag == PV B-frag for K=16, emulated via
// zero-padded 16x16x32). No LDS / barriers in main loop; LDS reduce at end.
__global__ __launch_bounds__(256) void pv_attn(
    const __hip_bfloat16* __restrict__ qt, const __hip_bfloat16* __restrict__ kt,
    const __hip_bfloat16* __restrict__ v,
    const float* __restrict__ rowM, const float* __restrict__ rowZi,
    const float* __restrict__ x, float* __restrict__ out)
{
    const int b = blockIdx.z, c0 = blockIdx.y * 64, n0 = blockIdx.x * 64;
    const int tid = threadIdx.x, lane = tid & 63, w = tid >> 6;
    const int lg = lane >> 4, lr = lane & 15;
    const __hip_bfloat16* qtb = qt + (size_t)b * N_ * CB_;
    const __hip_bfloat16* ktb = kt + (size_t)b * N_ * CB_;
    const __hip_bfloat16* vb  = v  + (size_t)b * C_ * N_;
    const float* Mb = rowM  + (size_t)b * N_;
    const float* Zb = rowZi + (size_t)b * N_;
    const f32x4 zero = {0.f, 0.f, 0.f, 0.f};

    bf16x8 kf[4];
#pragma unroll
    for (int nf = 0; nf < 4; ++nf)
        kf[nf] = ld_bf8(ktb + (size_t)(n0 + nf * 16 + lr) * CB_ + lg * 8);

    f32x4 acc[4][4] = {};
    const int mbase = w * 16;

    bf16x8 qf = ld_bf8(qtb + (size_t)(mbase + lr) * CB_ + lg * 8);
    float4 Mv = *reinterpret_cast<const float4*>(Mb + mbase + lg * 4);
    float4 Zv = *reinterpret_cast<const float4*>(Zb + mbase + lg * 4);

    for (int m0 = 0; m0 < N_; m0 += 64) {
        const int mrow = m0 + mbase;
        // V fragments for this step (needed late -> issue first)
        uint2 vld[4];
#pragma unroll
        for (int cf = 0; cf < 4; ++cf)
            vld[cf] = *reinterpret_cast<const uint2*>(
                &vb[(size_t)(c0 + cf * 16 + lr) * N_ + mrow + lg * 4]);
        // prefetch next step's q / M / Z (wraps harmlessly on last iter)
        const int mnext = (mrow + 64) & (N_ - 1);
        bf16x8 qf_n = ld_bf8(qtb + (size_t)(mnext + lr) * CB_ + lg * 8);
        float4 Mv_n = *reinterpret_cast<const float4*>(Mb + mnext + lg * 4);
        float4 Zv_n = *reinterpret_cast<const float4*>(Zb + mnext + lg * 4);

        const float mv[4] = {Mv.x, Mv.y, Mv.z, Mv.w};
        const float zv[4] = {Zv.x, Zv.y, Zv.z, Zv.w};
        // S (16m x 64n) -> P in registers (B-frag layout, upper K half zero)
        bf16x8 pb[4];
#pragma unroll
        for (int nf = 0; nf < 4; ++nf) {
            f32x4 sf = __builtin_amdgcn_mfma_f32_16x16x32_bf16(qf, kf[nf], zero, 0, 0, 0);
            union { __hip_bfloat16 h[8]; short s[8]; bf16x8 vv; } pk;
#pragma unroll
            for (int i = 0; i < 4; ++i)
                pk.h[i] = __float2bfloat16(__expf(sf[i] - mv[i]) * zv[i]);
            pk.s[4] = 0; pk.s[5] = 0; pk.s[6] = 0; pk.s[7] = 0;
            pb[nf] = pk.vv;
        }
        // PV: acc[cf][nf] += V[c, m-slice] * P[m-slice, n]
#pragma unroll
        for (int cf = 0; cf < 4; ++cf) {
            union { unsigned u[4]; bf16x8 vv; } av;
            av.u[0] = vld[cf].x; av.u[1] = vld[cf].y; av.u[2] = 0; av.u[3] = 0;
#pragma unroll
            for (int nf = 0; nf < 4; ++nf)
                acc[cf][nf] = __builtin_amdgcn_mfma_f32_16x16x32_bf16(av.vv, pb[nf], acc[cf][nf], 0, 0, 0);
        }
        qf = qf_n; Mv = Mv_n; Zv = Zv_n;
    }

    // Cross-wave reduction: R[n][c], stride 68 floats (16B-aligned rows of 4)
    __shared__ __attribute__((aligned(16))) float R[64][68];
#pragma unroll 1
    for (int ww = 0; ww < 4; ++ww) {
        if (w == ww) {
#pragma unroll
            for (int cf = 0; cf < 4; ++cf)
#pragma unroll
                for (int nf = 0; nf < 4; ++nf) {
                    float* dst = &R[nf * 16 + lr][cf * 16 + lg * 4];
                    if (ww == 0) *reinterpret_cast<f32x4*>(dst) = acc[cf][nf];
                    else {
                        f32x4 old = *reinterpret_cast<f32x4*>(dst);
                        *reinterpret_cast<f32x4*>(dst) = old + acc[cf][nf];
                    }
                }
        }
        __syncthreads();
    }
    // Epilogue: out = R + x, wave w writes c rows [w*16, w*16+16)
#pragma unroll
    for (int cr = 0; cr < 16; ++cr) {
        const int c = w * 16 + cr;
        const size_t idx = ((size_t)b * C_ + c0 + c) * N_ + n0 + lane;
        out[idx] = R[lane][c] + x[idx];
    }
}

extern "C" void kernel_launch(void* const* d_in, const int* in_sizes, int n_in,
                              void* d_out, int out_size, void* d_ws, size_t ws_size,
                              hipStream_t stream)
{
    const float* x  = (const float*)d_in[0];
    const float* Wq = (const float*)d_in[1];
    const float* bq = (const float*)d_in[2];
    const float* Wk = (const float*)d_in[3];
    const float* bk = (const float*)d_in[4];
    const float* Wv = (const float*)d_in[5];
    const float* bv = (const float*)d_in[6];
    float* out = (float*)d_out;

    char* ws = (char*)d_ws;
    __hip_bfloat16* Wc    = (__hip_bfloat16*)(ws);
    __hip_bfloat16* qt    = (__hip_bfloat16*)(ws + 0x040000);
    __hip_bfloat16* kt    = (__hip_bfloat16*)(ws + 0x140000);
    float*          rowM  = (float*)(ws + 0x240000);
    float*          rowZi = (float*)(ws + 0x250000);
    float*          pM    = (float*)(ws + 0x260000);
    float*          pZ    = (float*)(ws + 0x2A0000);
    __hip_bfloat16* vw    = (__hip_bfloat16*)(ws + 0x400000);

    wconv<<<80, 256, 0, stream>>>(Wq, Wk, Wv, Wc);
    qkv_gemm<<<dim3(N_ / 32, B_), 256, 0, stream>>>(x, Wc, bq, bk, bv, qt, kt, vw);
    row_stats_part<<<dim3(N_ / 64, 4, B_), 256, 0, stream>>>(qt, kt, pM, pZ);
    stats_combine<<<B_ * N_ / 256, 256, 0, stream>>>(pM, pZ, rowM, rowZi);
    pv_attn<<<dim3(N_ / 64, C_ / 64, B_), 256, 0, stream>>>(qt, kt, vw, rowM, rowZi,
                                                            x, out);
}

// Round 4
// 195.084 us; speedup vs baseline: 1.0236x; 1.0236x over previous
//
#include <hip/hip_runtime.h>
#include <hip/hip_bf16.h>

#define B_  4
#define C_  256
#define CB_ 32
#define N_  4096

typedef short bf16x8 __attribute__((ext_vector_type(8)));
typedef float f32x4  __attribute__((ext_vector_type(4)));
typedef float f32x16 __attribute__((ext_vector_type(16)));

static __device__ __forceinline__ bf16x8 ld_bf8(const __hip_bfloat16* p) {
    return *reinterpret_cast<const bf16x8*>(p);
}
static __device__ __forceinline__ unsigned pk2(float a, float b) {
    union { __hip_bfloat16 h[2]; unsigned u; } z;
    z.h[0] = __float2bfloat16(a); z.h[1] = __float2bfloat16(b);
    return z.u;
}

// ---------------------------------------------------------------------------
// Workspace layout:
//   Wc    bf16 [320][256]  @ 0x000000 (160 KiB)
//   qt    bf16 [B][N][32]  @ 0x040000 (1 MiB)
//   kt    bf16 [B][N][32]  @ 0x140000 (1 MiB)
//   rowE  fp32 [B][N]      @ 0x240000 (64 KiB)   e(m) = M(m) + ln Z(m)
//   pM    fp32 [4][B][N]   @ 0x250000 (256 KiB)
//   pZ    fp32 [4][B][N]   @ 0x290000 (256 KiB)
//   v     bf16 [B][C][N]   @ 0x400000 (8 MiB)
// ---------------------------------------------------------------------------

__global__ __launch_bounds__(256) void wconv(
    const float* __restrict__ Wq, const float* __restrict__ Wk,
    const float* __restrict__ Wv, __hip_bfloat16* __restrict__ Wc)
{
    int idx = (blockIdx.x * 256 + threadIdx.x) * 4;
    if (idx >= 320 * 256) return;
    int o = idx >> 8, c = idx & 255;
    const float* src = o < 32 ? Wq + o * 256 + c
                     : o < 64 ? Wk + (o - 32) * 256 + c
                              : Wv + (o - 64) * 256 + c;
    float4 f = *reinterpret_cast<const float4*>(src);
    union { __hip_bfloat16 h[4]; uint2 u; } pk;
    pk.h[0] = __float2bfloat16(f.x); pk.h[1] = __float2bfloat16(f.y);
    pk.h[2] = __float2bfloat16(f.z); pk.h[3] = __float2bfloat16(f.w);
    *reinterpret_cast<uint2*>(Wc + idx) = pk.u;
}

// Fused QKV projection, MFMA 16x16x32. Block: 32 n, all 320 output rows.
__global__ __launch_bounds__(256) void qkv_gemm(
    const float* __restrict__ x, const __hip_bfloat16* __restrict__ Wc,
    const float* __restrict__ bq, const float* __restrict__ bk,
    const float* __restrict__ bv,
    __hip_bfloat16* __restrict__ qt, __hip_bfloat16* __restrict__ kt,
    __hip_bfloat16* __restrict__ v)
{
    const int b = blockIdx.y, n0 = blockIdx.x * 32;
    const int tid = threadIdx.x, lane = tid & 63, w = tid >> 6;
    const int lg = lane >> 4, lr = lane & 15;
    __shared__ __attribute__((aligned(16))) __hip_bfloat16 T[2][32][40]; // [n][c]
    const float* xb = x + (size_t)b * C_ * N_;

    f32x4 acc[5][2] = {};
    for (int s = 0; s < 8; ++s) {
        const int c0 = s * 32, buf = s & 1;
        {
            int cl = tid >> 3, n4 = (tid & 7) * 4;
            float4 f = *reinterpret_cast<const float4*>(
                &xb[(size_t)(c0 + cl) * N_ + n0 + n4]);
            T[buf][n4 + 0][cl] = __float2bfloat16(f.x);
            T[buf][n4 + 1][cl] = __float2bfloat16(f.y);
            T[buf][n4 + 2][cl] = __float2bfloat16(f.z);
            T[buf][n4 + 3][cl] = __float2bfloat16(f.w);
        }
        __syncthreads();
        bf16x8 bfr[2];
#pragma unroll
        for (int nf = 0; nf < 2; ++nf)
            bfr[nf] = *reinterpret_cast<const bf16x8*>(&T[buf][nf * 16 + lr][lg * 8]);
#pragma unroll
        for (int t = 0; t < 5; ++t) {
            const int of = w + 4 * t;
            bf16x8 af = ld_bf8(Wc + (size_t)(of * 16 + lr) * 256 + c0 + lg * 8);
#pragma unroll
            for (int nf = 0; nf < 2; ++nf)
                acc[t][nf] = __builtin_amdgcn_mfma_f32_16x16x32_bf16(af, bfr[nf], acc[t][nf], 0, 0, 0);
        }
        __syncthreads();
    }
#pragma unroll
    for (int t = 0; t < 5; ++t) {
        const int of = w + 4 * t, ob = of * 16 + lg * 4;
        float bias[4];
#pragma unroll
        for (int i = 0; i < 4; ++i) {
            int o = ob + i;
            bias[i] = o < 32 ? bq[o] : o < 64 ? bk[o - 32] : bv[o - 64];
        }
#pragma unroll
        for (int nf = 0; nf < 2; ++nf) {
            const int n = n0 + nf * 16 + lr;
            if (ob < 64) {
                union { __hip_bfloat16 h[4]; uint2 u; } pk;
#pragma unroll
                for (int i = 0; i < 4; ++i)
                    pk.h[i] = __float2bfloat16(acc[t][nf][i] + bias[i]);
                __hip_bfloat16* dst = ob < 32
                    ? qt + ((size_t)b * N_ + n) * CB_ + ob
                    : kt + ((size_t)b * N_ + n) * CB_ + (ob - 32);
                *reinterpret_cast<uint2*>(dst) = pk.u;
            } else {
#pragma unroll
                for (int i = 0; i < 4; ++i)
                    v[((size_t)b * C_ + (ob - 64 + i)) * N_ + n] =
                        __float2bfloat16(acc[t][nf][i] + bias[i]);
            }
        }
    }
}

// Partial row stats over an n-quarter (16x16x32 MFMA). Wave w: 16 m-rows.
__global__ __launch_bounds__(256) void row_stats_part(
    const __hip_bfloat16* __restrict__ qt, const __hip_bfloat16* __restrict__ kt,
    float* __restrict__ pM, float* __restrict__ pZ)
{
    const int m0 = blockIdx.x * 64, s = blockIdx.y, b = blockIdx.z;
    const int tid = threadIdx.x, lane = tid & 63, w = tid >> 6;
    const int lg = lane >> 4, lr = lane & 15;
    const __hip_bfloat16* qtb = qt + (size_t)b * N_ * CB_;
    const __hip_bfloat16* ktb = kt + (size_t)b * N_ * CB_;
    const int mrow = m0 + w * 16;
    bf16x8 qf = ld_bf8(qtb + (size_t)(mrow + lr) * CB_ + lg * 8);
    float rm[4] = {-1e30f, -1e30f, -1e30f, -1e30f};
    float rz[4] = {0.f, 0.f, 0.f, 0.f};
    const f32x4 zero = {0.f, 0.f, 0.f, 0.f};
    const int nbeg = s * (N_ / 4);
    for (int n = nbeg; n < nbeg + N_ / 4; n += 64) {
        f32x4 sf[4];
#pragma unroll
        for (int nf = 0; nf < 4; ++nf) {
            bf16x8 kf = ld_bf8(ktb + (size_t)(n + nf * 16 + lr) * CB_ + lg * 8);
            sf[nf] = __builtin_amdgcn_mfma_f32_16x16x32_bf16(qf, kf, zero, 0, 0, 0);
        }
#pragma unroll
        for (int i = 0; i < 4; ++i) {
            float tm = fmaxf(fmaxf(sf[0][i], sf[1][i]), fmaxf(sf[2][i], sf[3][i]));
            if (tm > rm[i]) { rz[i] *= __expf(rm[i] - tm); rm[i] = tm; }
            rz[i] += __expf(sf[0][i] - rm[i]) + __expf(sf[1][i] - rm[i]) +
                     __expf(sf[2][i] - rm[i]) + __expf(sf[3][i] - rm[i]);
        }
    }
#pragma unroll
    for (int off = 1; off < 16; off <<= 1) {
#pragma unroll
        for (int i = 0; i < 4; ++i) {
            float om = __shfl_xor(rm[i], off);
            float oz = __shfl_xor(rz[i], off);
            float nm = fmaxf(rm[i], om);
            rz[i] = rz[i] * __expf(rm[i] - nm) + oz * __expf(om - nm);
            rm[i] = nm;
        }
    }
    if (lr == 0) {
        const size_t base = ((size_t)s * B_ + b) * N_ + mrow + lg * 4;
#pragma unroll
        for (int i = 0; i < 4; ++i) { pM[base + i] = rm[i]; pZ[base + i] = rz[i]; }
    }
}

__global__ __launch_bounds__(256) void stats_combine(
    const float* __restrict__ pM, const float* __restrict__ pZ,
    float* __restrict__ rowE)
{
    const int i = blockIdx.x * 256 + threadIdx.x;   // over B_*N_
    const int BN = B_ * N_;
    float m0 = pM[i], m1 = pM[BN + i], m2 = pM[2 * BN + i], m3 = pM[3 * BN + i];
    float M = fmaxf(fmaxf(m0, m1), fmaxf(m2, m3));
    float Z = pZ[i]          * __expf(m0 - M) + pZ[BN + i]     * __expf(m1 - M)
            + pZ[2 * BN + i] * __expf(m2 - M) + pZ[3 * BN + i] * __expf(m3 - M);
    rowE[i] = M + logf(Z);
}

// out[c,n] = x[c,n] + sum_m v[c,m] * exp(S(m,n) - e(m)).
// Block: 128c x 64n; waves (wm, wn) in 2x2: wm splits m (interleaved 32-windows),
// wn splits n (32-col slices). 32x32x16 MFMAs; P kept in registers and repacked
// to the PV B-fragment with v_permlane32_swap_b32 (full K=32 PV, no LDS in loop).
__global__ __launch_bounds__(256, 2) void pv_attn(
    const __hip_bfloat16* __restrict__ qt, const __hip_bfloat16* __restrict__ kt,
    const __hip_bfloat16* __restrict__ v, const float* __restrict__ rowE,
    const float* __restrict__ x, float* __restrict__ out)
{
    const int b = blockIdx.z, c0 = blockIdx.y * 128, n0 = blockIdx.x * 64;
    const int tid = threadIdx.x, lane = tid & 63;
    const int w = tid >> 6, wn = w & 1, wm = w >> 1;
    const int h = lane >> 5, l31 = lane & 31;
    const __hip_bfloat16* qtb = qt + (size_t)b * N_ * CB_;
    const __hip_bfloat16* ktb = kt + (size_t)b * N_ * CB_;
    const __hip_bfloat16* vb  = v  + (size_t)b * C_ * N_;
    const float* ep = rowE + (size_t)b * N_ + 4 * h;

    // K B-frags for this wave's n-slice (loop-invariant)
    const int nrow = n0 + wn * 32;
    bf16x8 kB0 = ld_bf8(ktb + (size_t)(nrow + l31) * CB_ + h * 8);
    bf16x8 kB1 = ld_bf8(ktb + (size_t)(nrow + l31) * CB_ + h * 8 + 16);

    const __hip_bfloat16* qp = qtb + (size_t)(wm * 32 + l31) * CB_ + h * 8;
    const __hip_bfloat16* vp[4];
#pragma unroll
    for (int ct = 0; ct < 4; ++ct)
        vp[ct] = vb + (size_t)(c0 + ct * 32 + l31) * N_ + wm * 32 + h * 8;

    f32x16 acc[4] = {};

    // step-0 operands
    bf16x8 qA0 = ld_bf8(qp), qA1 = ld_bf8(qp + 16);
    bf16x8 vA[4][2];
#pragma unroll
    for (int ct = 0; ct < 4; ++ct) {
        vA[ct][0] = ld_bf8(vp[ct]); vA[ct][1] = ld_bf8(vp[ct] + 16);
    }
    int mrow = wm * 32;
    f32x4 e[4];
#pragma unroll
    for (int g = 0; g < 4; ++g)
        e[g] = *reinterpret_cast<const f32x4*>(ep + mrow + 8 * g);

    for (int t = 0; t < 64; ++t) {
        const int na = (t < 63) ? 64 : 0;          // next-step advance (clamped)
        // prefetch next step (independent of current compute)
        bf16x8 qn0 = ld_bf8(qp + (size_t)na * CB_);
        bf16x8 qn1 = ld_bf8(qp + (size_t)na * CB_ + 16);
        bf16x8 vn[4][2];
#pragma unroll
        for (int ct = 0; ct < 4; ++ct) {
            vn[ct][0] = ld_bf8(vp[ct] + na);
            vn[ct][1] = ld_bf8(vp[ct] + na + 16);
        }
        f32x4 en[4];
#pragma unroll
        for (int g = 0; g < 4; ++g)
            en[g] = *reinterpret_cast<const f32x4*>(ep + mrow + na + 8 * g);

        // S tile (32m x 32n), K=32 over two chained MFMAs
        f32x16 sf = {};
        sf = __builtin_amdgcn_mfma_f32_32x32x16_bf16(qA0, kB0, sf, 0, 0, 0);
        sf = __builtin_amdgcn_mfma_f32_32x32x16_bf16(qA1, kB1, sf, 0, 0, 0);

        // P = exp(S - e(m)), pack pairs to bf16 words
        unsigned W[8];
#pragma unroll
        for (int g = 0; g < 4; ++g) {
            float p0 = __expf(sf[4 * g + 0] - e[g][0]);
            float p1 = __expf(sf[4 * g + 1] - e[g][1]);
            float p2 = __expf(sf[4 * g + 2] - e[g][2]);
            float p3 = __expf(sf[4 * g + 3] - e[g][3]);
            W[2 * g + 0] = pk2(p0, p1);
            W[2 * g + 1] = pk2(p2, p3);
        }
        // cross-half exchange: a' = [a.lo|b.lo], b' = [a.hi|b.hi]
        asm("v_permlane32_swap_b32 %0, %1" : "+v"(W[0]), "+v"(W[2]));
        asm("v_permlane32_swap_b32 %0, %1" : "+v"(W[1]), "+v"(W[3]));
        asm("v_permlane32_swap_b32 %0, %1" : "+v"(W[4]), "+v"(W[6]));
        asm("v_permlane32_swap_b32 %0, %1" : "+v"(W[5]), "+v"(W[7]));
        union { unsigned u[4]; bf16x8 v8; } f0, f1;
        f0.u[0] = W[0]; f0.u[1] = W[1]; f0.u[2] = W[2]; f0.u[3] = W[3];
        f1.u[0] = W[4]; f1.u[1] = W[5]; f1.u[2] = W[6]; f1.u[3] = W[7];

        // PV: full K=32 (two K=16 MFMAs per c-tile)
#pragma unroll
        for (int ct = 0; ct < 4; ++ct) {
            acc[ct] = __builtin_amdgcn_mfma_f32_32x32x16_bf16(vA[ct][0], f0.v8, acc[ct], 0, 0, 0);
            acc[ct] = __builtin_amdgcn_mfma_f32_32x32x16_bf16(vA[ct][1], f1.v8, acc[ct], 0, 0, 0);
        }
        // rotate prefetched operands
        qA0 = qn0; qA1 = qn1;
#pragma unroll
        for (int ct = 0; ct < 4; ++ct) {
            vA[ct][0] = vn[ct][0]; vA[ct][1] = vn[ct][1]; vp[ct] += na;
        }
#pragma unroll
        for (int g = 0; g < 4; ++g) e[g] = en[g];
        qp += (size_t)na * CB_;
        mrow += na;
    }

    // 2-way wm-reduce through LDS, then cooperative epilogue
    __shared__ __attribute__((aligned(16))) float R[128][68];
    if (wm == 1) {
#pragma unroll
        for (int ct = 0; ct < 4; ++ct)
#pragma unroll
            for (int i = 0; i < 16; ++i) {
                int cl = 32 * ct + (i & 3) + 8 * (i >> 2) + 4 * h;
                R[cl][wn * 32 + l31] = acc[ct][i];
            }
    }
    __syncthreads();
    if (wm == 0) {
#pragma unroll
        for (int ct = 0; ct < 4; ++ct)
#pragma unroll
            for (int i = 0; i < 16; ++i) {
                int cl = 32 * ct + (i & 3) + 8 * (i >> 2) + 4 * h;
                R[cl][wn * 32 + l31] += acc[ct][i];
            }
    }
    __syncthreads();
    const int tr = tid >> 4, n4 = (tid & 15) * 4;
#pragma unroll
    for (int rr = 0; rr < 8; ++rr) {
        const int c = tr + rr * 16;
        f32x4 rv = *reinterpret_cast<const f32x4*>(&R[c][n4]);
        const size_t gi = ((size_t)b * C_ + c0 + c) * N_ + n0 + n4;
        f32x4 xv = *reinterpret_cast<const f32x4*>(x + gi);
        *reinterpret_cast<f32x4*>(out + gi) = rv + xv;
    }
}

extern "C" void kernel_launch(void* const* d_in, const int* in_sizes, int n_in,
                              void* d_out, int out_size, void* d_ws, size_t ws_size,
                              hipStream_t stream)
{
    const float* x  = (const float*)d_in[0];
    const float* Wq = (const float*)d_in[1];
    const float* bq = (const float*)d_in[2];
    const float* Wk = (const float*)d_in[3];
    const float* bk = (const float*)d_in[4];
    const float* Wv = (const float*)d_in[5];
    const float* bv = (const float*)d_in[6];
    float* out = (float*)d_out;

    char* ws = (char*)d_ws;
    __hip_bfloat16* Wc   = (__hip_bfloat16*)(ws);
    __hip_bfloat16* qt   = (__hip_bfloat16*)(ws + 0x040000);
    __hip_bfloat16* kt   = (__hip_bfloat16*)(ws + 0x140000);
    float*          rowE = (float*)(ws + 0x240000);
    float*          pM   = (float*)(ws + 0x250000);
    float*          pZ   = (float*)(ws + 0x290000);
    __hip_bfloat16* vw   = (__hip_bfloat16*)(ws + 0x400000);

    wconv<<<80, 256, 0, stream>>>(Wq, Wk, Wv, Wc);
    qkv_gemm<<<dim3(N_ / 32, B_), 256, 0, stream>>>(x, Wc, bq, bk, bv, qt, kt, vw);
    row_stats_part<<<dim3(N_ / 64, 4, B_), 256, 0, stream>>>(qt, kt, pM, pZ);
    stats_combine<<<B_ * N_ / 256, 256, 0, stream>>>(pM, pZ, rowE);
    pv_attn<<<dim3(N_ / 64, C_ / 128, B_), 256, 0, stream>>>(qt, kt, vw, rowE, x, out);
}

// Round 6
// 178.930 us; speedup vs baseline: 1.1160x; 1.0903x over previous
//
#include <hip/hip_runtime.h>
#include <hip/hip_bf16.h>

#define B_  4
#define C_  256
#define CB_ 32
#define N_  4096

typedef short bf16x8 __attribute__((ext_vector_type(8)));
typedef float f32x4  __attribute__((ext_vector_type(4)));
typedef float f32x16 __attribute__((ext_vector_type(16)));

static __device__ __forceinline__ bf16x8 ld_bf8(const __hip_bfloat16* p) {
    return *reinterpret_cast<const bf16x8*>(p);
}
static __device__ __forceinline__ unsigned pk2(float a, float b) {
    union { __hip_bfloat16 h[2]; unsigned u; } z;
    z.h[0] = __float2bfloat16(a); z.h[1] = __float2bfloat16(b);
    return z.u;
}

// ---------------------------------------------------------------------------
// Workspace layout:
//   Wc    bf16 [320][256]        @ 0x000000 (160 KiB)
//   qt    bf16 [B][N][32]        @ 0x040000 (1 MiB)
//   kt    bf16 [B][N][32]        @ 0x140000 (1 MiB)
//   rowE  fp32 [B][N]            @ 0x240000 (64 KiB)  e(m) = M(m) + ln Z(m)
//   pM    fp32 [4][B][N]         @ 0x250000 (256 KiB)
//   pZ    fp32 [4][B][N]         @ 0x290000 (256 KiB)
//   v     bf16 [B][N/32][C][32]  @ 0x400000 (8 MiB)   32-m panels
// ---------------------------------------------------------------------------

__global__ __launch_bounds__(256) void wconv(
    const float* __restrict__ Wq, const float* __restrict__ Wk,
    const float* __restrict__ Wv, __hip_bfloat16* __restrict__ Wc)
{
    int idx = (blockIdx.x * 256 + threadIdx.x) * 4;
    if (idx >= 320 * 256) return;
    int o = idx >> 8, c = idx & 255;
    const float* src = o < 32 ? Wq + o * 256 + c
                     : o < 64 ? Wk + (o - 32) * 256 + c
                              : Wv + (o - 64) * 256 + c;
    float4 f = *reinterpret_cast<const float4*>(src);
    union { __hip_bfloat16 h[4]; uint2 u; } pk;
    pk.h[0] = __float2bfloat16(f.x); pk.h[1] = __float2bfloat16(f.y);
    pk.h[2] = __float2bfloat16(f.z); pk.h[3] = __float2bfloat16(f.w);
    *reinterpret_cast<uint2*>(Wc + idx) = pk.u;
}

// Fused QKV projection, MFMA 16x16x32. Block: 32 n, all 320 output rows.
// v written in 32-m panel layout. (R4 numerics: q unscaled.)
__global__ __launch_bounds__(256) void qkv_gemm(
    const float* __restrict__ x, const __hip_bfloat16* __restrict__ Wc,
    const float* __restrict__ bq, const float* __restrict__ bk,
    const float* __restrict__ bv,
    __hip_bfloat16* __restrict__ qt, __hip_bfloat16* __restrict__ kt,
    __hip_bfloat16* __restrict__ v)
{
    const int b = blockIdx.y, n0 = blockIdx.x * 32;
    const int tid = threadIdx.x, lane = tid & 63, w = tid >> 6;
    const int lg = lane >> 4, lr = lane & 15;
    __shared__ __attribute__((aligned(16))) __hip_bfloat16 T[2][32][40]; // [n][c]
    const float* xb = x + (size_t)b * C_ * N_;

    f32x4 acc[5][2] = {};
    for (int s = 0; s < 8; ++s) {
        const int c0 = s * 32, buf = s & 1;
        {
            int cl = tid >> 3, n4 = (tid & 7) * 4;
            float4 f = *reinterpret_cast<const float4*>(
                &xb[(size_t)(c0 + cl) * N_ + n0 + n4]);
            T[buf][n4 + 0][cl] = __float2bfloat16(f.x);
            T[buf][n4 + 1][cl] = __float2bfloat16(f.y);
            T[buf][n4 + 2][cl] = __float2bfloat16(f.z);
            T[buf][n4 + 3][cl] = __float2bfloat16(f.w);
        }
        __syncthreads();
        bf16x8 bfr[2];
#pragma unroll
        for (int nf = 0; nf < 2; ++nf)
            bfr[nf] = *reinterpret_cast<const bf16x8*>(&T[buf][nf * 16 + lr][lg * 8]);
#pragma unroll
        for (int t = 0; t < 5; ++t) {
            const int of = w + 4 * t;
            bf16x8 af = ld_bf8(Wc + (size_t)(of * 16 + lr) * 256 + c0 + lg * 8);
#pragma unroll
            for (int nf = 0; nf < 2; ++nf)
                acc[t][nf] = __builtin_amdgcn_mfma_f32_16x16x32_bf16(af, bfr[nf], acc[t][nf], 0, 0, 0);
        }
        __syncthreads();
    }
#pragma unroll
    for (int t = 0; t < 5; ++t) {
        const int of = w + 4 * t, ob = of * 16 + lg * 4;
        float bias[4];
#pragma unroll
        for (int i = 0; i < 4; ++i) {
            int o = ob + i;
            bias[i] = o < 32 ? bq[o] : o < 64 ? bk[o - 32] : bv[o - 64];
        }
#pragma unroll
        for (int nf = 0; nf < 2; ++nf) {
            const int n = n0 + nf * 16 + lr;
            if (ob < 64) {
                union { __hip_bfloat16 h[4]; uint2 u; } pk;
#pragma unroll
                for (int i = 0; i < 4; ++i)
                    pk.h[i] = __float2bfloat16(acc[t][nf][i] + bias[i]);
                __hip_bfloat16* dst = ob < 32
                    ? qt + ((size_t)b * N_ + n) * CB_ + ob
                    : kt + ((size_t)b * N_ + n) * CB_ + (ob - 32);
                *reinterpret_cast<uint2*>(dst) = pk.u;
            } else {    // v -> panel layout [b][n/32][C][32]
                const size_t pbase = ((size_t)(b * (N_ / 32) + (n0 >> 5)) * C_);
#pragma unroll
                for (int i = 0; i < 4; ++i)
                    v[(pbase + (ob - 64 + i)) * 32 + nf * 16 + lr] =
                        __float2bfloat16(acc[t][nf][i] + bias[i]);
            }
        }
    }
}

// Partial row stats over an n-quarter (16x16x32 MFMA). Wave w: 16 m-rows.
__global__ __launch_bounds__(256) void row_stats_part(
    const __hip_bfloat16* __restrict__ qt, const __hip_bfloat16* __restrict__ kt,
    float* __restrict__ pM, float* __restrict__ pZ)
{
    const int m0 = blockIdx.x * 64, s = blockIdx.y, b = blockIdx.z;
    const int tid = threadIdx.x, lane = tid & 63, w = tid >> 6;
    const int lg = lane >> 4, lr = lane & 15;
    const __hip_bfloat16* qtb = qt + (size_t)b * N_ * CB_;
    const __hip_bfloat16* ktb = kt + (size_t)b * N_ * CB_;
    const int mrow = m0 + w * 16;
    bf16x8 qf = ld_bf8(qtb + (size_t)(mrow + lr) * CB_ + lg * 8);
    float rm[4] = {-1e30f, -1e30f, -1e30f, -1e30f};
    float rz[4] = {0.f, 0.f, 0.f, 0.f};
    const f32x4 zero = {0.f, 0.f, 0.f, 0.f};
    const int nbeg = s * (N_ / 4);
    for (int n = nbeg; n < nbeg + N_ / 4; n += 64) {
        f32x4 sf[4];
#pragma unroll
        for (int nf = 0; nf < 4; ++nf) {
            bf16x8 kf = ld_bf8(ktb + (size_t)(n + nf * 16 + lr) * CB_ + lg * 8);
            sf[nf] = __builtin_amdgcn_mfma_f32_16x16x32_bf16(qf, kf, zero, 0, 0, 0);
        }
#pragma unroll
        for (int i = 0; i < 4; ++i) {
            float tm = fmaxf(fmaxf(sf[0][i], sf[1][i]), fmaxf(sf[2][i], sf[3][i]));
            if (tm > rm[i]) { rz[i] *= __expf(rm[i] - tm); rm[i] = tm; }
            rz[i] += __expf(sf[0][i] - rm[i]) + __expf(sf[1][i] - rm[i]) +
                     __expf(sf[2][i] - rm[i]) + __expf(sf[3][i] - rm[i]);
        }
    }
#pragma unroll
    for (int off = 1; off < 16; off <<= 1) {
#pragma unroll
        for (int i = 0; i < 4; ++i) {
            float om = __shfl_xor(rm[i], off);
            float oz = __shfl_xor(rz[i], off);
            float nm = fmaxf(rm[i], om);
            rz[i] = rz[i] * __expf(rm[i] - nm) + oz * __expf(om - nm);
            rm[i] = nm;
        }
    }
    if (lr == 0) {
        const size_t base = ((size_t)s * B_ + b) * N_ + mrow + lg * 4;
#pragma unroll
        for (int i = 0; i < 4; ++i) { pM[base + i] = rm[i]; pZ[base + i] = rz[i]; }
    }
}

__global__ __launch_bounds__(256) void stats_combine(
    const float* __restrict__ pM, const float* __restrict__ pZ,
    float* __restrict__ rowE)
{
    const int i = blockIdx.x * 256 + threadIdx.x;   // over B_*N_
    const int BN = B_ * N_;
    float m0 = pM[i], m1 = pM[BN + i], m2 = pM[2 * BN + i], m3 = pM[3 * BN + i];
    float M = fmaxf(fmaxf(m0, m1), fmaxf(m2, m3));
    float Z = pZ[i]          * __expf(m0 - M) + pZ[BN + i]     * __expf(m1 - M)
            + pZ[2 * BN + i] * __expf(m2 - M) + pZ[3 * BN + i] * __expf(m3 - M);
    rowE[i] = M + logf(Z);
}

// out[c,n] = x[c,n] + sum_m v[c,m] * exp(S(m,n) - e(m)).
// Block: 64c x 64n, 8 waves = 4 m-splits (ms) x 2 n-halves (nf).
// Wave (ms,nf): S(32m x 32n) for m-windows ms*32 + 128t, n-slice nf*32.
// 32x32x16 MFMAs; P register-resident via v_permlane32_swap_b32 (R4-proven);
// V in 32-m panel layout (lane-contiguous fragment loads).
__global__ __launch_bounds__(512) void pv_attn(
    const __hip_bfloat16* __restrict__ qt, const __hip_bfloat16* __restrict__ kt,
    const __hip_bfloat16* __restrict__ vv, const float* __restrict__ rowE,
    const float* __restrict__ x, float* __restrict__ out)
{
    const int b = blockIdx.z, c0 = blockIdx.y * 64, n0 = blockIdx.x * 64;
    const int tid = threadIdx.x, lane = tid & 63, w = tid >> 6;
    const int ms = w >> 1, nf = w & 1;
    const int h = lane >> 5, l31 = lane & 31;
    const __hip_bfloat16* qtb = qt + (size_t)b * N_ * CB_;
    const __hip_bfloat16* ktb = kt + (size_t)b * N_ * CB_;
    const __hip_bfloat16* vbase = vv + (size_t)b * (N_ / 32) * C_ * 32;
    const float* ep = rowE + (size_t)b * N_ + 4 * h;

    // K B-frags for this wave's n-slice (loop-invariant)
    bf16x8 kB0 = ld_bf8(ktb + (size_t)(n0 + nf * 32 + l31) * CB_ + h * 8);
    bf16x8 kB1 = ld_bf8(ktb + (size_t)(n0 + nf * 32 + l31) * CB_ + h * 8 + 16);

    const __hip_bfloat16* qp  = qtb + (size_t)(ms * 32 + l31) * CB_ + h * 8;
    const __hip_bfloat16* vp0 = vbase + ((size_t)ms * C_ + c0 + l31) * 32 + h * 8;
    const __hip_bfloat16* vp1 = vbase + ((size_t)ms * C_ + c0 + 32 + l31) * 32 + h * 8;
    int mrow = ms * 32;

    f32x16 acc0 = {}, acc1 = {};
    bf16x8 qA0 = ld_bf8(qp), qA1 = ld_bf8(qp + 16);
    bf16x8 vA00 = ld_bf8(vp0), vA01 = ld_bf8(vp0 + 16);
    bf16x8 vA10 = ld_bf8(vp1), vA11 = ld_bf8(vp1 + 16);

    for (int t = 0; t < 32; ++t) {
        const int na = (t < 31) ? 128 : 0;     // 4 windows of 32 per step
        const size_t qa = (size_t)na * CB_;    // qt elements
        const size_t va = (size_t)na * 256;    // v elements (4 panels)
        // prefetch next step's Q and V
        bf16x8 qn0 = ld_bf8(qp + qa), qn1 = ld_bf8(qp + qa + 16);
        bf16x8 vn00 = ld_bf8(vp0 + va), vn01 = ld_bf8(vp0 + va + 16);
        bf16x8 vn10 = ld_bf8(vp1 + va), vn11 = ld_bf8(vp1 + va + 16);
        // e for this step's 32 rows
        f32x4 e0 = *reinterpret_cast<const f32x4*>(ep + mrow);
        f32x4 e1 = *reinterpret_cast<const f32x4*>(ep + mrow + 8);
        f32x4 e2 = *reinterpret_cast<const f32x4*>(ep + mrow + 16);
        f32x4 e3 = *reinterpret_cast<const f32x4*>(ep + mrow + 24);

        // S tile (32m x 32n), K=32 over two chained MFMAs
        f32x16 sf = {};
        sf = __builtin_amdgcn_mfma_f32_32x32x16_bf16(qA0, kB0, sf, 0, 0, 0);
        sf = __builtin_amdgcn_mfma_f32_32x32x16_bf16(qA1, kB1, sf, 0, 0, 0);

        // P = exp(S - e), packed to bf16 words (rows 8g+4h+{0..3} per group g)
        unsigned W0 = pk2(__expf(sf[0]  - e0[0]), __expf(sf[1]  - e0[1]));
        unsigned W1 = pk2(__expf(sf[2]  - e0[2]), __expf(sf[3]  - e0[3]));
        unsigned W2 = pk2(__expf(sf[4]  - e1[0]), __expf(sf[5]  - e1[1]));
        unsigned W3 = pk2(__expf(sf[6]  - e1[2]), __expf(sf[7]  - e1[3]));
        unsigned W4 = pk2(__expf(sf[8]  - e2[0]), __expf(sf[9]  - e2[1]));
        unsigned W5 = pk2(__expf(sf[10] - e2[2]), __expf(sf[11] - e2[3]));
        unsigned W6 = pk2(__expf(sf[12] - e3[0]), __expf(sf[13] - e3[1]));
        unsigned W7 = pk2(__expf(sf[14] - e3[2]), __expf(sf[15] - e3[3]));
        asm("v_permlane32_swap_b32 %0, %1" : "+v"(W0), "+v"(W2));
        asm("v_permlane32_swap_b32 %0, %1" : "+v"(W1), "+v"(W3));
        asm("v_permlane32_swap_b32 %0, %1" : "+v"(W4), "+v"(W6));
        asm("v_permlane32_swap_b32 %0, %1" : "+v"(W5), "+v"(W7));
        union { unsigned u[4]; bf16x8 v8; } f0, f1;
        f0.u[0] = W0; f0.u[1] = W1; f0.u[2] = W2; f0.u[3] = W3;
        f1.u[0] = W4; f1.u[1] = W5; f1.u[2] = W6; f1.u[3] = W7;

        // PV: full K=32
        acc0 = __builtin_amdgcn_mfma_f32_32x32x16_bf16(vA00, f0.v8, acc0, 0, 0, 0);
        acc0 = __builtin_amdgcn_mfma_f32_32x32x16_bf16(vA01, f1.v8, acc0, 0, 0, 0);
        acc1 = __builtin_amdgcn_mfma_f32_32x32x16_bf16(vA10, f0.v8, acc1, 0, 0, 0);
        acc1 = __builtin_amdgcn_mfma_f32_32x32x16_bf16(vA11, f1.v8, acc1, 0, 0, 0);

        // rotate prefetched operands
        qA0 = qn0; qA1 = qn1;
        vA00 = vn00; vA01 = vn01; vA10 = vn10; vA11 = vn11;
        qp += qa; vp0 += va; vp1 += va; mrow += na;
    }

    // 4-phase ms-reduction through LDS (nf pair writes disjoint columns)
    __shared__ __attribute__((aligned(16))) float R[64][68];
#pragma unroll 1
    for (int p = 3; p >= 0; --p) {
        if (ms == p) {
#pragma unroll
            for (int i = 0; i < 16; ++i) {
                const int cl = (i & 3) + 8 * (i >> 2) + 4 * h;
                const int nn = nf * 32 + l31;
                if (p == 3) { R[cl][nn] = acc0[i];  R[cl + 32][nn] = acc1[i]; }
                else        { R[cl][nn] += acc0[i]; R[cl + 32][nn] += acc1[i]; }
            }
        }
        __syncthreads();
    }
    // epilogue: out = R + x
    const int cr = tid >> 3, n8 = (tid & 7) * 8;
#pragma unroll
    for (int j = 0; j < 8; j += 4) {
        f32x4 rv = *reinterpret_cast<const f32x4*>(&R[cr][n8 + j]);
        const size_t gi = ((size_t)b * C_ + c0 + cr) * N_ + n0 + n8 + j;
        f32x4 xv = *reinterpret_cast<const f32x4*>(x + gi);
        *reinterpret_cast<f32x4*>(out + gi) = rv + xv;
    }
}

extern "C" void kernel_launch(void* const* d_in, const int* in_sizes, int n_in,
                              void* d_out, int out_size, void* d_ws, size_t ws_size,
                              hipStream_t stream)
{
    const float* x  = (const float*)d_in[0];
    const float* Wq = (const float*)d_in[1];
    const float* bq = (const float*)d_in[2];
    const float* Wk = (const float*)d_in[3];
    const float* bk = (const float*)d_in[4];
    const float* Wv = (const float*)d_in[5];
    const float* bv = (const float*)d_in[6];
    float* out = (float*)d_out;

    char* ws = (char*)d_ws;
    __hip_bfloat16* Wc   = (__hip_bfloat16*)(ws);
    __hip_bfloat16* qt   = (__hip_bfloat16*)(ws + 0x040000);
    __hip_bfloat16* kt   = (__hip_bfloat16*)(ws + 0x140000);
    float*          rowE = (float*)(ws + 0x240000);
    float*          pM   = (float*)(ws + 0x250000);
    float*          pZ   = (float*)(ws + 0x290000);
    __hip_bfloat16* vw   = (__hip_bfloat16*)(ws + 0x400000);

    wconv<<<80, 256, 0, stream>>>(Wq, Wk, Wv, Wc);
    qkv_gemm<<<dim3(N_ / 32, B_), 256, 0, stream>>>(x, Wc, bq, bk, bv, qt, kt, vw);
    row_stats_part<<<dim3(N_ / 64, 4, B_), 256, 0, stream>>>(qt, kt, pM, pZ);
    stats_combine<<<B_ * N_ / 256, 256, 0, stream>>>(pM, pZ, rowE);
    pv_attn<<<dim3(N_ / 64, C_ / 64, B_), 512, 0, stream>>>(qt, kt, vw, rowE, x, out);
}

// Round 8
// 162.715 us; speedup vs baseline: 1.2272x; 1.0997x over previous
//
#include <hip/hip_runtime.h>
#include <hip/hip_bf16.h>

#define B_  4
#define C_  256
#define CB_ 32
#define N_  4096

typedef short bf16x8 __attribute__((ext_vector_type(8)));
typedef float f32x4  __attribute__((ext_vector_type(4)));
typedef float f32x16 __attribute__((ext_vector_type(16)));

static __device__ __forceinline__ bf16x8 ld_bf8(const __hip_bfloat16* p) {
    return *reinterpret_cast<const bf16x8*>(p);
}
static __device__ __forceinline__ unsigned pk2(float a, float b) {
    union { __hip_bfloat16 h[2]; unsigned u; } z;
    z.h[0] = __float2bfloat16(a); z.h[1] = __float2bfloat16(b);
    return z.u;
}

// ---------------------------------------------------------------------------
// Workspace layout:
//   Wc    bf16 [320][256]        @ 0x000000 (160 KiB)
//   qt    bf16 [B][N][32]        @ 0x040000 (1 MiB)
//   kt    bf16 [B][N][32]        @ 0x140000 (1 MiB)
//   rowE  fp32 [B][N]            @ 0x240000 (64 KiB)  e(m) = M(m) + ln Z(m)
//   pM    fp32 [4][B][N]         @ 0x250000 (256 KiB)
//   pZ    fp32 [4][B][N]         @ 0x290000 (256 KiB)
//   v     bf16 [B][N/32][C][32]  @ 0x400000 (8 MiB)   32-m panels
// ---------------------------------------------------------------------------

__global__ __launch_bounds__(256) void wconv(
    const float* __restrict__ Wq, const float* __restrict__ Wk,
    const float* __restrict__ Wv, __hip_bfloat16* __restrict__ Wc)
{
    int idx = (blockIdx.x * 256 + threadIdx.x) * 4;
    if (idx >= 320 * 256) return;
    int o = idx >> 8, c = idx & 255;
    const float* src = o < 32 ? Wq + o * 256 + c
                     : o < 64 ? Wk + (o - 32) * 256 + c
                              : Wv + (o - 64) * 256 + c;
    float4 f = *reinterpret_cast<const float4*>(src);
    union { __hip_bfloat16 h[4]; uint2 u; } pk;
    pk.h[0] = __float2bfloat16(f.x); pk.h[1] = __float2bfloat16(f.y);
    pk.h[2] = __float2bfloat16(f.z); pk.h[3] = __float2bfloat16(f.w);
    *reinterpret_cast<uint2*>(Wc + idx) = pk.u;
}

// Fused QKV projection, MFMA 16x16x32. Block: 32 n, all 320 output rows.
// v written in 32-m panel layout.
__global__ __launch_bounds__(256) void qkv_gemm(
    const float* __restrict__ x, const __hip_bfloat16* __restrict__ Wc,
    const float* __restrict__ bq, const float* __restrict__ bk,
    const float* __restrict__ bv,
    __hip_bfloat16* __restrict__ qt, __hip_bfloat16* __restrict__ kt,
    __hip_bfloat16* __restrict__ v)
{
    const int b = blockIdx.y, n0 = blockIdx.x * 32;
    const int tid = threadIdx.x, lane = tid & 63, w = tid >> 6;
    const int lg = lane >> 4, lr = lane & 15;
    __shared__ __attribute__((aligned(16))) __hip_bfloat16 T[2][32][40]; // [n][c]
    const float* xb = x + (size_t)b * C_ * N_;

    f32x4 acc[5][2] = {};
    for (int s = 0; s < 8; ++s) {
        const int c0 = s * 32, buf = s & 1;
        {
            int cl = tid >> 3, n4 = (tid & 7) * 4;
            float4 f = *reinterpret_cast<const float4*>(
                &xb[(size_t)(c0 + cl) * N_ + n0 + n4]);
            T[buf][n4 + 0][cl] = __float2bfloat16(f.x);
            T[buf][n4 + 1][cl] = __float2bfloat16(f.y);
            T[buf][n4 + 2][cl] = __float2bfloat16(f.z);
            T[buf][n4 + 3][cl] = __float2bfloat16(f.w);
        }
        __syncthreads();
        bf16x8 bfr[2];
#pragma unroll
        for (int nf = 0; nf < 2; ++nf)
            bfr[nf] = *reinterpret_cast<const bf16x8*>(&T[buf][nf * 16 + lr][lg * 8]);
#pragma unroll
        for (int t = 0; t < 5; ++t) {
            const int of = w + 4 * t;
            bf16x8 af = ld_bf8(Wc + (size_t)(of * 16 + lr) * 256 + c0 + lg * 8);
#pragma unroll
            for (int nf = 0; nf < 2; ++nf)
                acc[t][nf] = __builtin_amdgcn_mfma_f32_16x16x32_bf16(af, bfr[nf], acc[t][nf], 0, 0, 0);
        }
        __syncthreads();
    }
#pragma unroll
    for (int t = 0; t < 5; ++t) {
        const int of = w + 4 * t, ob = of * 16 + lg * 4;
        float bias[4];
#pragma unroll
        for (int i = 0; i < 4; ++i) {
            int o = ob + i;
            bias[i] = o < 32 ? bq[o] : o < 64 ? bk[o - 32] : bv[o - 64];
        }
#pragma unroll
        for (int nf = 0; nf < 2; ++nf) {
            const int n = n0 + nf * 16 + lr;
            if (ob < 64) {
                union { __hip_bfloat16 h[4]; uint2 u; } pk;
#pragma unroll
                for (int i = 0; i < 4; ++i)
                    pk.h[i] = __float2bfloat16(acc[t][nf][i] + bias[i]);
                __hip_bfloat16* dst = ob < 32
                    ? qt + ((size_t)b * N_ + n) * CB_ + ob
                    : kt + ((size_t)b * N_ + n) * CB_ + (ob - 32);
                *reinterpret_cast<uint2*>(dst) = pk.u;
            } else {    // v -> panel layout [b][n/32][C][32]
                const size_t pbase = ((size_t)(b * (N_ / 32) + (n0 >> 5)) * C_);
#pragma unroll
                for (int i = 0; i < 4; ++i)
                    v[(pbase + (ob - 64 + i)) * 32 + nf * 16 + lr] =
                        __float2bfloat16(acc[t][nf][i] + bias[i]);
            }
        }
    }
}

// Partial row stats over an n-quarter (16x16x32 MFMA). Wave w: 16 m-rows.
__global__ __launch_bounds__(256) void row_stats_part(
    const __hip_bfloat16* __restrict__ qt, const __hip_bfloat16* __restrict__ kt,
    float* __restrict__ pM, float* __restrict__ pZ)
{
    const int m0 = blockIdx.x * 64, s = blockIdx.y, b = blockIdx.z;
    const int tid = threadIdx.x, lane = tid & 63, w = tid >> 6;
    const int lg = lane >> 4, lr = lane & 15;
    const __hip_bfloat16* qtb = qt + (size_t)b * N_ * CB_;
    const __hip_bfloat16* ktb = kt + (size_t)b * N_ * CB_;
    const int mrow = m0 + w * 16;
    bf16x8 qf = ld_bf8(qtb + (size_t)(mrow + lr) * CB_ + lg * 8);
    float rm[4] = {-1e30f, -1e30f, -1e30f, -1e30f};
    float rz[4] = {0.f, 0.f, 0.f, 0.f};
    const f32x4 zero = {0.f, 0.f, 0.f, 0.f};
    const int nbeg = s * (N_ / 4);
    for (int n = nbeg; n < nbeg + N_ / 4; n += 64) {
        f32x4 sf[4];
#pragma unroll
        for (int nf = 0; nf < 4; ++nf) {
            bf16x8 kf = ld_bf8(ktb + (size_t)(n + nf * 16 + lr) * CB_ + lg * 8);
            sf[nf] = __builtin_amdgcn_mfma_f32_16x16x32_bf16(qf, kf, zero, 0, 0, 0);
        }
#pragma unroll
        for (int i = 0; i < 4; ++i) {
            float tm = fmaxf(fmaxf(sf[0][i], sf[1][i]), fmaxf(sf[2][i], sf[3][i]));
            if (tm > rm[i]) { rz[i] *= __expf(rm[i] - tm); rm[i] = tm; }
            rz[i] += __expf(sf[0][i] - rm[i]) + __expf(sf[1][i] - rm[i]) +
                     __expf(sf[2][i] - rm[i]) + __expf(sf[3][i] - rm[i]);
        }
    }
#pragma unroll
    for (int off = 1; off < 16; off <<= 1) {
#pragma unroll
        for (int i = 0; i < 4; ++i) {
            float om = __shfl_xor(rm[i], off);
            float oz = __shfl_xor(rz[i], off);
            float nm = fmaxf(rm[i], om);
            rz[i] = rz[i] * __expf(rm[i] - nm) + oz * __expf(om - nm);
            rm[i] = nm;
        }
    }
    if (lr == 0) {
        const size_t base = ((size_t)s * B_ + b) * N_ + mrow + lg * 4;
#pragma unroll
        for (int i = 0; i < 4; ++i) { pM[base + i] = rm[i]; pZ[base + i] = rz[i]; }
    }
}

__global__ __launch_bounds__(256) void stats_combine(
    const float* __restrict__ pM, const float* __restrict__ pZ,
    float* __restrict__ rowE)
{
    const int i = blockIdx.x * 256 + threadIdx.x;   // over B_*N_
    const int BN = B_ * N_;
    float m0 = pM[i], m1 = pM[BN + i], m2 = pM[2 * BN + i], m3 = pM[3 * BN + i];
    float M = fmaxf(fmaxf(m0, m1), fmaxf(m2, m3));
    float Z = pZ[i]          * __expf(m0 - M) + pZ[BN + i]     * __expf(m1 - M)
            + pZ[2 * BN + i] * __expf(m2 - M) + pZ[3 * BN + i] * __expf(m3 - M);
    rowE[i] = M + logf(Z);
}

// out[c,n] = x[c,n] + sum_m v[c,m] * exp(S(m,n) - e(m)).
// Block: 128c x 64n, 8 waves = 4 m-splits (ms) x 2 n-halves (nf).
// Each wave: one S tile (32m x 32n) feeds PV for 4 c-tiles (8 PV MFMAs per
// 2 S MFMAs). P register-resident via v_permlane32_swap_b32; V in 32-m panel
// layout (lane-contiguous fragment loads). NO launch_bounds min-wave clamp and
// NO unroll pragma: clamped-into-spill builds of this kernel miscompiled
// (R5/R7 absmax ~3-4); unclamped low-pressure builds pass (R4/R6).
__global__ __launch_bounds__(512) void pv_attn(
    const __hip_bfloat16* __restrict__ qt, const __hip_bfloat16* __restrict__ kt,
    const __hip_bfloat16* __restrict__ vv, const float* __restrict__ rowE,
    const float* __restrict__ x, float* __restrict__ out)
{
    const int b = blockIdx.z, c0 = blockIdx.y * 128, n0 = blockIdx.x * 64;
    const int tid = threadIdx.x, lane = tid & 63, w = tid >> 6;
    const int ms = w >> 1, nf = w & 1;
    const int h = lane >> 5, l31 = lane & 31;
    const __hip_bfloat16* qtb = qt + (size_t)b * N_ * CB_;
    const __hip_bfloat16* ktb = kt + (size_t)b * N_ * CB_;
    const __hip_bfloat16* vbase = vv + (size_t)b * (N_ / 32) * C_ * 32;
    const float* ep = rowE + (size_t)b * N_ + 4 * h;

    // K B-frags for this wave's n-slice (loop-invariant)
    bf16x8 kB0 = ld_bf8(ktb + (size_t)(n0 + nf * 32 + l31) * CB_ + h * 8);
    bf16x8 kB1 = ld_bf8(ktb + (size_t)(n0 + nf * 32 + l31) * CB_ + h * 8 + 16);

    const __hip_bfloat16* qp = qtb + (size_t)(ms * 32 + l31) * CB_ + h * 8;
    const __hip_bfloat16* vp[4];
#pragma unroll
    for (int ct = 0; ct < 4; ++ct)
        vp[ct] = vbase + ((size_t)ms * C_ + c0 + ct * 32 + l31) * 32 + h * 8;
    int mrow = ms * 32;

    f32x16 acc[4] = {};
    bf16x8 qA0 = ld_bf8(qp), qA1 = ld_bf8(qp + 16);
    bf16x8 vA[4][2];
#pragma unroll
    for (int ct = 0; ct < 4; ++ct) {
        vA[ct][0] = ld_bf8(vp[ct]); vA[ct][1] = ld_bf8(vp[ct] + 16);
    }

    for (int t = 0; t < 32; ++t) {
        const int na = (t < 31) ? 128 : 0;     // 4 m-windows of 32 per step
        const size_t qa = (size_t)na * CB_;    // qt elements
        const size_t va = (size_t)na * 256;    // v elements (4 panels)
        // prefetch next step's Q and V
        bf16x8 qn0 = ld_bf8(qp + qa), qn1 = ld_bf8(qp + qa + 16);
        bf16x8 vn[4][2];
#pragma unroll
        for (int ct = 0; ct < 4; ++ct) {
            vn[ct][0] = ld_bf8(vp[ct] + va);
            vn[ct][1] = ld_bf8(vp[ct] + va + 16);
        }
        // e for this step's 32 rows
        f32x4 e0 = *reinterpret_cast<const f32x4*>(ep + mrow);
        f32x4 e1 = *reinterpret_cast<const f32x4*>(ep + mrow + 8);
        f32x4 e2 = *reinterpret_cast<const f32x4*>(ep + mrow + 16);
        f32x4 e3 = *reinterpret_cast<const f32x4*>(ep + mrow + 24);

        // S tile (32m x 32n), K=32 over two chained MFMAs
        f32x16 sf = {};
        sf = __builtin_amdgcn_mfma_f32_32x32x16_bf16(qA0, kB0, sf, 0, 0, 0);
        sf = __builtin_amdgcn_mfma_f32_32x32x16_bf16(qA1, kB1, sf, 0, 0, 0);

        // P = exp(S - e), packed to bf16 words (rows 8g+4h+{0..3} per group g)
        unsigned W0 = pk2(__expf(sf[0]  - e0[0]), __expf(sf[1]  - e0[1]));
        unsigned W1 = pk2(__expf(sf[2]  - e0[2]), __expf(sf[3]  - e0[3]));
        unsigned W2 = pk2(__expf(sf[4]  - e1[0]), __expf(sf[5]  - e1[1]));
        unsigned W3 = pk2(__expf(sf[6]  - e1[2]), __expf(sf[7]  - e1[3]));
        unsigned W4 = pk2(__expf(sf[8]  - e2[0]), __expf(sf[9]  - e2[1]));
        unsigned W5 = pk2(__expf(sf[10] - e2[2]), __expf(sf[11] - e2[3]));
        unsigned W6 = pk2(__expf(sf[12] - e3[0]), __expf(sf[13] - e3[1]));
        unsigned W7 = pk2(__expf(sf[14] - e3[2]), __expf(sf[15] - e3[3]));
        asm("v_permlane32_swap_b32 %0, %1" : "+v"(W0), "+v"(W2));
        asm("v_permlane32_swap_b32 %0, %1" : "+v"(W1), "+v"(W3));
        asm("v_permlane32_swap_b32 %0, %1" : "+v"(W4), "+v"(W6));
        asm("v_permlane32_swap_b32 %0, %1" : "+v"(W5), "+v"(W7));
        union { unsigned u[4]; bf16x8 v8; } f0, f1;
        f0.u[0] = W0; f0.u[1] = W1; f0.u[2] = W2; f0.u[3] = W3;
        f1.u[0] = W4; f1.u[1] = W5; f1.u[2] = W6; f1.u[3] = W7;

        // PV: full K=32, 4 c-tiles
#pragma unroll
        for (int ct = 0; ct < 4; ++ct) {
            acc[ct] = __builtin_amdgcn_mfma_f32_32x32x16_bf16(vA[ct][0], f0.v8, acc[ct], 0, 0, 0);
            acc[ct] = __builtin_amdgcn_mfma_f32_32x32x16_bf16(vA[ct][1], f1.v8, acc[ct], 0, 0, 0);
        }
        // rotate prefetched operands
        qA0 = qn0; qA1 = qn1;
#pragma unroll
        for (int ct = 0; ct < 4; ++ct) {
            vA[ct][0] = vn[ct][0]; vA[ct][1] = vn[ct][1]; vp[ct] += va;
        }
        qp += qa; mrow += na;
    }

    // 4-phase ms-reduction through LDS (nf pair writes disjoint columns)
    __shared__ __attribute__((aligned(16))) float R[128][68];
#pragma unroll 1
    for (int p = 3; p >= 0; --p) {
        if (ms == p) {
#pragma unroll
            for (int i = 0; i < 16; ++i) {
                const int cl = (i & 3) + 8 * (i >> 2) + 4 * h;
                const int nn = nf * 32 + l31;
#pragma unroll
                for (int ct = 0; ct < 4; ++ct) {
                    if (p == 3) R[ct * 32 + cl][nn] = acc[ct][i];
                    else        R[ct * 32 + cl][nn] += acc[ct][i];
                }
            }
        }
        __syncthreads();
    }
    // epilogue: out = R + x (128 rows x 64 cols, 16 floats/thread)
    const int cr = tid >> 2, n16 = (tid & 3) * 16;
#pragma unroll
    for (int j = 0; j < 4; ++j) {
        f32x4 rv = *reinterpret_cast<const f32x4*>(&R[cr][n16 + 4 * j]);
        const size_t gi = ((size_t)b * C_ + c0 + cr) * N_ + n0 + n16 + 4 * j;
        f32x4 xv = *reinterpret_cast<const f32x4*>(x + gi);
        *reinterpret_cast<f32x4*>(out + gi) = rv + xv;
    }
}

extern "C" void kernel_launch(void* const* d_in, const int* in_sizes, int n_in,
                              void* d_out, int out_size, void* d_ws, size_t ws_size,
                              hipStream_t stream)
{
    const float* x  = (const float*)d_in[0];
    const float* Wq = (const float*)d_in[1];
    const float* bq = (const float*)d_in[2];
    const float* Wk = (const float*)d_in[3];
    const float* bk = (const float*)d_in[4];
    const float* Wv = (const float*)d_in[5];
    const float* bv = (const float*)d_in[6];
    float* out = (float*)d_out;

    char* ws = (char*)d_ws;
    __hip_bfloat16* Wc   = (__hip_bfloat16*)(ws);
    __hip_bfloat16* qt   = (__hip_bfloat16*)(ws + 0x040000);
    __hip_bfloat16* kt   = (__hip_bfloat16*)(ws + 0x140000);
    float*          rowE = (float*)(ws + 0x240000);
    float*          pM   = (float*)(ws + 0x250000);
    float*          pZ   = (float*)(ws + 0x290000);
    __hip_bfloat16* vw   = (__hip_bfloat16*)(ws + 0x400000);

    wconv<<<80, 256, 0, stream>>>(Wq, Wk, Wv, Wc);
    qkv_gemm<<<dim3(N_ / 32, B_), 256, 0, stream>>>(x, Wc, bq, bk, bv, qt, kt, vw);
    row_stats_part<<<dim3(N_ / 64, 4, B_), 256, 0, stream>>>(qt, kt, pM, pZ);
    stats_combine<<<B_ * N_ / 256, 256, 0, stream>>>(pM, pZ, rowE);
    pv_attn<<<dim3(N_ / 64, C_ / 128, B_), 512, 0, stream>>>(qt, kt, vw, rowE, x, out);
}